// Round 7
// baseline (61.550 us; speedup 1.0000x reference)
//
#include <hip/hip_runtime.h>

// Problem constants (match reference)
#define N_NODES  4096
#define MAX_PATH 5
#define EDGE_DIM 16

typedef int   iv2 __attribute__((ext_vector_type(2)));
typedef float fv2 __attribute__((ext_vector_type(2)));
typedef float fv4 __attribute__((ext_vector_type(4)));

#define ZERO_BLOCKS 2048
#define BLOCK 256

// Phase 0: precompute D[l][e] = dot(edge_attr[e], edge_vector[l]) (f32).
// 2 MB table -> L2-resident for the gather phase.
__global__ __launch_bounds__(256) void precompute_dots_kernel(
    const float* __restrict__ edge_attr,   // [E, 16]
    const float* __restrict__ edge_vector, // [MAX_PATH, 16]
    float*       __restrict__ D,           // [MAX_PATH, E]
    int n_edges)
{
    int e = blockIdx.x * blockDim.x + threadIdx.x;
    if (e >= n_edges) return;

    const float4* ea = (const float4*)(edge_attr + (size_t)e * EDGE_DIM);
    float4 a0 = ea[0], a1 = ea[1], a2 = ea[2], a3 = ea[3];

#pragma unroll
    for (int l = 0; l < MAX_PATH; ++l) {
        const float4* ev = (const float4*)(edge_vector + l * EDGE_DIM);
        float4 b0 = ev[0], b1 = ev[1], b2 = ev[2], b3 = ev[3];
        float d = a0.x*b0.x + a0.y*b0.y + a0.z*b0.z + a0.w*b0.w
                + a1.x*b1.x + a1.y*b1.y + a1.z*b1.z + a1.w*b1.w
                + a2.x*b2.x + a2.y*b2.y + a2.z*b2.z + a2.w*b2.w
                + a3.x*b3.x + a3.y*b3.y + a3.z*b3.z + a3.w*b3.w;
        D[(size_t)l * n_edges + e] = d;
    }
}

// Phase A (fused): blocks [0, ZERO_BLOCKS) zero-fill `out` with non-temporal
// 16B stores (streaming; don't evict the hot D table). Remaining blocks
// gather 2 pairs/thread from the L2-resident D and write vals[] coalesced.
// Disjoint buffers -> no intra-kernel ordering needed. The runtime's
// fillBufferAligned ran at 1.6 TB/s / 8.6% occupancy; this fill saturates.
__global__ __launch_bounds__(256) void zero_and_gather_kernel(
    const float* __restrict__ D,        // [MAX_PATH, E]
    const int*   __restrict__ path_idx, // [P, MAX_PATH]
    float*       __restrict__ vals,     // [P]
    float*       __restrict__ out,      // [N_NODES, N_NODES]
    int n_pairs, int n_edges)
{
    if ((int)blockIdx.x < ZERO_BLOCKS) {
        // 16.7M floats = 4.19M fv4 stores over 2048*256 threads (8 iters).
        const size_t nvec   = (size_t)N_NODES * N_NODES / 4;
        const size_t stride = (size_t)ZERO_BLOCKS * BLOCK;
        fv4 z = {0.f, 0.f, 0.f, 0.f};
        fv4* o4 = (fv4*)out;
        for (size_t i = (size_t)blockIdx.x * BLOCK + threadIdx.x; i < nvec; i += stride)
            __builtin_nontemporal_store(z, o4 + i);
        return;
    }

    int t  = ((int)blockIdx.x - ZERO_BLOCKS) * BLOCK + threadIdx.x;
    int p0 = t * 2;
    if (p0 >= n_pairs) return;

    // 10 path ints for 2 pairs = 5 aligned 8B loads.
    const iv2* pp = (const iv2*)(path_idx + (size_t)p0 * MAX_PATH);
    iv2 w0 = pp[0], w1 = pp[1], w2 = pp[2], w3 = pp[3], w4 = pp[4];
    int e[10] = { w0.x, w0.y, w1.x, w1.y, w2.x,
                  w2.y, w3.x, w3.y, w4.x, w4.y };

    float g[10];
#pragma unroll
    for (int j = 0; j < 2; ++j) {
#pragma unroll
        for (int l = 0; l < MAX_PATH; ++l) {
            int idx = e[j * MAX_PATH + l];
            g[j * MAX_PATH + l] = (idx >= 0) ? D[(size_t)l * n_edges + idx] : 0.0f;
        }
    }

    fv2 v;
#pragma unroll
    for (int j = 0; j < 2; ++j) {
        float sum = 0.0f;
        int   cnt = 0;
#pragma unroll
        for (int l = 0; l < MAX_PATH; ++l) {
            if (e[j * MAX_PATH + l] >= 0) { sum += g[j * MAX_PATH + l]; ++cnt; }
        }
        v[j] = (cnt > 0) ? (sum / (float)cnt) : 0.0f;
    }
    *(fv2*)(vals + p0) = v;   // coalesced 8B store
}

// Phase B: scatter-only. Coalesced float4/int4 reads, 4 random stores/thread.
// Kernel boundary guarantees the zero-fill is complete.
__global__ __launch_bounds__(256) void scatter_vals_kernel(
    const float* __restrict__ vals,     // [P]
    const int*   __restrict__ src_idx,  // [P]
    const int*   __restrict__ dst_idx,  // [P]
    float*       __restrict__ out,      // [N_NODES, N_NODES]
    int n_pairs)
{
    int t  = blockIdx.x * blockDim.x + threadIdx.x;
    int p0 = t * 4;
    if (p0 >= n_pairs) return;

    if (p0 + 3 < n_pairs) {
        float4 v  = *(const float4*)(vals + p0);
        int4   sv = *(const int4*)(src_idx + p0);
        int4   dv = *(const int4*)(dst_idx + p0);
        out[(size_t)sv.x * N_NODES + dv.x] = v.x;
        out[(size_t)sv.y * N_NODES + dv.y] = v.y;
        out[(size_t)sv.z * N_NODES + dv.z] = v.z;
        out[(size_t)sv.w * N_NODES + dv.w] = v.w;
    } else {
        for (int p = p0; p < n_pairs; ++p)
            out[(size_t)src_idx[p] * N_NODES + dst_idx[p]] = vals[p];
    }
}

extern "C" void kernel_launch(void* const* d_in, const int* in_sizes, int n_in,
                              void* d_out, int out_size, void* d_ws, size_t ws_size,
                              hipStream_t stream)
{
    // Input order: x, edge_attr, edge_vector, src_idx, dst_idx, path_idx
    const float* edge_attr   = (const float*)d_in[1];
    const float* edge_vector = (const float*)d_in[2];
    const int*   src_idx     = (const int*)d_in[3];
    const int*   dst_idx     = (const int*)d_in[4];
    const int*   path_idx    = (const int*)d_in[5];
    float*       out         = (float*)d_out;

    const int n_edges = in_sizes[1] / EDGE_DIM;  // 100,000
    const int n_pairs = in_sizes[3];             // 1,000,000

    float* D    = (float*)d_ws;                         // 5*E*4B = 2 MB
    float* vals = (float*)((char*)d_ws +
                  (((size_t)5 * n_edges * sizeof(float) + 1023) & ~(size_t)1023));

    precompute_dots_kernel<<<(n_edges + BLOCK - 1) / BLOCK, BLOCK, 0, stream>>>(
        edge_attr, edge_vector, D, n_edges);

    const int gather_blocks = ((n_pairs + 1) / 2 + BLOCK - 1) / BLOCK;
    zero_and_gather_kernel<<<ZERO_BLOCKS + gather_blocks, BLOCK, 0, stream>>>(
        D, path_idx, vals, out, n_pairs, n_edges);

    const int tB = (n_pairs + 3) / 4;
    scatter_vals_kernel<<<(tB + BLOCK - 1) / BLOCK, BLOCK, 0, stream>>>(
        vals, src_idx, dst_idx, out, n_pairs);
}

// Round 8
// 53.564 us; speedup vs baseline: 1.1491x; 1.1491x over previous
//
#include <hip/hip_runtime.h>

// Problem constants (match reference)
#define N_NODES  4096
#define MAX_PATH 5
#define EDGE_DIM 16

typedef int   iv2 __attribute__((ext_vector_type(2)));
typedef float fv2 __attribute__((ext_vector_type(2)));
typedef float fv4 __attribute__((ext_vector_type(4)));

#define BLOCK 256
#define FILL_BLOCKS 2048

// Custom zero-fill with NORMAL cached stores: saturates HBM (runtime's
// fillBufferAligned ran 1.6 TB/s @ 8.6% occupancy) AND leaves out-lines
// in L2 so the later scatter's random 4B RMWs hit L2 instead of HBM.
__global__ __launch_bounds__(256) void fill_zero_kernel(float* __restrict__ out)
{
    const size_t nvec   = (size_t)N_NODES * N_NODES / 4;
    const size_t stride = (size_t)FILL_BLOCKS * BLOCK;
    fv4 z = {0.f, 0.f, 0.f, 0.f};
    fv4* o4 = (fv4*)out;
    for (size_t i = (size_t)blockIdx.x * BLOCK + threadIdx.x; i < nvec; i += stride)
        o4[i] = z;
}

// Precompute D[l][e] = dot(edge_attr[e], edge_vector[l]) (f32, 2 MB).
// Runs AFTER the fill so D is L2-hot when the gather starts.
__global__ __launch_bounds__(256) void precompute_dots_kernel(
    const float* __restrict__ edge_attr,   // [E, 16]
    const float* __restrict__ edge_vector, // [MAX_PATH, 16]
    float*       __restrict__ D,           // [MAX_PATH, E]
    int n_edges)
{
    int e = blockIdx.x * blockDim.x + threadIdx.x;
    if (e >= n_edges) return;

    const float4* ea = (const float4*)(edge_attr + (size_t)e * EDGE_DIM);
    float4 a0 = ea[0], a1 = ea[1], a2 = ea[2], a3 = ea[3];

#pragma unroll
    for (int l = 0; l < MAX_PATH; ++l) {
        const float4* ev = (const float4*)(edge_vector + l * EDGE_DIM);
        float4 b0 = ev[0], b1 = ev[1], b2 = ev[2], b3 = ev[3];
        float d = a0.x*b0.x + a0.y*b0.y + a0.z*b0.z + a0.w*b0.w
                + a1.x*b1.x + a1.y*b1.y + a1.z*b1.z + a1.w*b1.w
                + a2.x*b2.x + a2.y*b2.y + a2.z*b2.z + a2.w*b2.w
                + a3.x*b3.x + a3.y*b3.y + a3.z*b3.z + a3.w*b3.w;
        D[(size_t)l * n_edges + e] = d;
    }
}

// Gather-only: 2 pairs/thread, int2 path loads, up to 10 independent
// L2-resident D gathers, mean, coalesced vals[] write. No random stores.
__global__ __launch_bounds__(256) void gather_vals_kernel(
    const float* __restrict__ D,        // [MAX_PATH, E]
    const int*   __restrict__ path_idx, // [P, MAX_PATH]
    float*       __restrict__ vals,     // [P]
    int n_pairs, int n_edges)
{
    int t  = blockIdx.x * blockDim.x + threadIdx.x;
    int p0 = t * 2;
    if (p0 >= n_pairs) return;

    const iv2* pp = (const iv2*)(path_idx + (size_t)p0 * MAX_PATH);
    iv2 w0 = pp[0], w1 = pp[1], w2 = pp[2], w3 = pp[3], w4 = pp[4];
    int e[10] = { w0.x, w0.y, w1.x, w1.y, w2.x,
                  w2.y, w3.x, w3.y, w4.x, w4.y };

    float g[10];
#pragma unroll
    for (int j = 0; j < 2; ++j) {
#pragma unroll
        for (int l = 0; l < MAX_PATH; ++l) {
            int idx = e[j * MAX_PATH + l];
            g[j * MAX_PATH + l] = (idx >= 0) ? D[(size_t)l * n_edges + idx] : 0.0f;
        }
    }

    fv2 v;
#pragma unroll
    for (int j = 0; j < 2; ++j) {
        float sum = 0.0f;
        int   cnt = 0;
#pragma unroll
        for (int l = 0; l < MAX_PATH; ++l) {
            if (e[j * MAX_PATH + l] >= 0) { sum += g[j * MAX_PATH + l]; ++cnt; }
        }
        v[j] = (cnt > 0) ? (sum / (float)cnt) : 0.0f;
    }
    *(fv2*)(vals + p0) = v;   // coalesced 8B store
}

// Scatter-only: coalesced float4/int4 reads, 4 random stores/thread.
// out-lines still warm in L2 from the fill -> stores mostly L2 hits.
__global__ __launch_bounds__(256) void scatter_vals_kernel(
    const float* __restrict__ vals,     // [P]
    const int*   __restrict__ src_idx,  // [P]
    const int*   __restrict__ dst_idx,  // [P]
    float*       __restrict__ out,      // [N_NODES, N_NODES]
    int n_pairs)
{
    int t  = blockIdx.x * blockDim.x + threadIdx.x;
    int p0 = t * 4;
    if (p0 >= n_pairs) return;

    if (p0 + 3 < n_pairs) {
        float4 v  = *(const float4*)(vals + p0);
        int4   sv = *(const int4*)(src_idx + p0);
        int4   dv = *(const int4*)(dst_idx + p0);
        out[(size_t)sv.x * N_NODES + dv.x] = v.x;
        out[(size_t)sv.y * N_NODES + dv.y] = v.y;
        out[(size_t)sv.z * N_NODES + dv.z] = v.z;
        out[(size_t)sv.w * N_NODES + dv.w] = v.w;
    } else {
        for (int p = p0; p < n_pairs; ++p)
            out[(size_t)src_idx[p] * N_NODES + dst_idx[p]] = vals[p];
    }
}

extern "C" void kernel_launch(void* const* d_in, const int* in_sizes, int n_in,
                              void* d_out, int out_size, void* d_ws, size_t ws_size,
                              hipStream_t stream)
{
    // Input order: x, edge_attr, edge_vector, src_idx, dst_idx, path_idx
    const float* edge_attr   = (const float*)d_in[1];
    const float* edge_vector = (const float*)d_in[2];
    const int*   src_idx     = (const int*)d_in[3];
    const int*   dst_idx     = (const int*)d_in[4];
    const int*   path_idx    = (const int*)d_in[5];
    float*       out         = (float*)d_out;

    const int n_edges = in_sizes[1] / EDGE_DIM;  // 100,000
    const int n_pairs = in_sizes[3];             // 1,000,000

    float* D    = (float*)d_ws;                         // 5*E*4B = 2 MB
    float* vals = (float*)((char*)d_ws +
                  (((size_t)5 * n_edges * sizeof(float) + 1023) & ~(size_t)1023));

    // 1) fast zero-fill (normal stores -> out lines land dirty in L2)
    fill_zero_kernel<<<FILL_BLOCKS, BLOCK, 0, stream>>>(out);

    // 2) precompute D AFTER the fill so it's L2-hot for the gather
    precompute_dots_kernel<<<(n_edges + BLOCK - 1) / BLOCK, BLOCK, 0, stream>>>(
        edge_attr, edge_vector, D, n_edges);

    // 3) gather
    const int tA = (n_pairs + 1) / 2;
    gather_vals_kernel<<<(tA + BLOCK - 1) / BLOCK, BLOCK, 0, stream>>>(
        D, path_idx, vals, n_pairs, n_edges);

    // 4) scatter
    const int tB = (n_pairs + 3) / 4;
    scatter_vals_kernel<<<(tB + BLOCK - 1) / BLOCK, BLOCK, 0, stream>>>(
        vals, src_idx, dst_idx, out, n_pairs);
}

// Round 9
// 45.510 us; speedup vs baseline: 1.3525x; 1.1770x over previous
//
#include <hip/hip_runtime.h>

// Problem constants (match reference)
#define N_NODES  4096
#define MAX_PATH 5
#define EDGE_DIM 16

typedef int   iv2 __attribute__((ext_vector_type(2)));
typedef float fv4 __attribute__((ext_vector_type(4)));

#define BLOCK 256
#define FILL_BLOCKS 2048

// K1 (fused): blocks [0, FILL_BLOCKS) zero `out` with NORMAL cached float4
// stores (leaves lines in L2/L3 for the scatter; nt was -8us, R6). Blocks
// [FILL_BLOCKS, ...) precompute D[l][e] = dot(edge_attr[e], edge_vector[l]).
// Disjoint outputs -> no intra-kernel ordering required.
__global__ __launch_bounds__(256) void fill_and_precompute_kernel(
    const float* __restrict__ edge_attr,   // [E, 16]
    const float* __restrict__ edge_vector, // [MAX_PATH, 16]
    float*       __restrict__ D,           // [MAX_PATH, E]
    float*       __restrict__ out,         // [N_NODES, N_NODES]
    int n_edges)
{
    if ((int)blockIdx.x < FILL_BLOCKS) {
        const size_t nvec   = (size_t)N_NODES * N_NODES / 4;   // 4.19M fv4
        const size_t stride = (size_t)FILL_BLOCKS * BLOCK;
        fv4 z = {0.f, 0.f, 0.f, 0.f};
        fv4* o4 = (fv4*)out;
        for (size_t i = (size_t)blockIdx.x * BLOCK + threadIdx.x; i < nvec; i += stride)
            o4[i] = z;
        return;
    }

    int e = ((int)blockIdx.x - FILL_BLOCKS) * BLOCK + threadIdx.x;
    if (e >= n_edges) return;

    const float4* ea = (const float4*)(edge_attr + (size_t)e * EDGE_DIM);
    float4 a0 = ea[0], a1 = ea[1], a2 = ea[2], a3 = ea[3];

#pragma unroll
    for (int l = 0; l < MAX_PATH; ++l) {
        const float4* ev = (const float4*)(edge_vector + l * EDGE_DIM);
        float4 b0 = ev[0], b1 = ev[1], b2 = ev[2], b3 = ev[3];
        float d = a0.x*b0.x + a0.y*b0.y + a0.z*b0.z + a0.w*b0.w
                + a1.x*b1.x + a1.y*b1.y + a1.z*b1.z + a1.w*b1.w
                + a2.x*b2.x + a2.y*b2.y + a2.z*b2.z + a2.w*b2.w
                + a3.x*b3.x + a3.y*b3.y + a3.z*b3.z + a3.w*b3.w;
        D[(size_t)l * n_edges + e] = d;
    }
}

// K2 (fused): gather + scatter, 2 pairs/thread. 5x 8B path loads, up to 10
// independent D gathers (D is 2MB, L2-resident after K1), mean, then 2
// random stores into the L2/L3-warm out buffer. Pairs unique -> plain store.
__global__ __launch_bounds__(256) void gather_scatter_kernel(
    const float* __restrict__ D,        // [MAX_PATH, E]
    const int*   __restrict__ src_idx,  // [P]
    const int*   __restrict__ dst_idx,  // [P]
    const int*   __restrict__ path_idx, // [P, MAX_PATH]
    float*       __restrict__ out,      // [N_NODES, N_NODES]
    int n_pairs, int n_edges)
{
    int t  = blockIdx.x * blockDim.x + threadIdx.x;
    int p0 = t * 2;
    if (p0 >= n_pairs) return;

    if (p0 + 1 < n_pairs) {
        const iv2* pp = (const iv2*)(path_idx + (size_t)p0 * MAX_PATH);
        iv2 w0 = pp[0], w1 = pp[1], w2 = pp[2], w3 = pp[3], w4 = pp[4];
        int e[10] = { w0.x, w0.y, w1.x, w1.y, w2.x,
                      w2.y, w3.x, w3.y, w4.x, w4.y };

        float g[10];
#pragma unroll
        for (int j = 0; j < 2; ++j) {
#pragma unroll
            for (int l = 0; l < MAX_PATH; ++l) {
                int idx = e[j * MAX_PATH + l];
                g[j * MAX_PATH + l] = (idx >= 0) ? D[(size_t)l * n_edges + idx] : 0.0f;
            }
        }

        iv2 sv = *(const iv2*)(src_idx + p0);
        iv2 dv = *(const iv2*)(dst_idx + p0);
        int srcs[2] = { sv.x, sv.y };
        int dsts[2] = { dv.x, dv.y };

#pragma unroll
        for (int j = 0; j < 2; ++j) {
            float sum = 0.0f;
            int   cnt = 0;
#pragma unroll
            for (int l = 0; l < MAX_PATH; ++l) {
                if (e[j * MAX_PATH + l] >= 0) { sum += g[j * MAX_PATH + l]; ++cnt; }
            }
            float val = (cnt > 0) ? (sum / (float)cnt) : 0.0f;
            out[(size_t)srcs[j] * N_NODES + dsts[j]] = val;
        }
    } else {
        for (int p = p0; p < n_pairs; ++p) {
            float sum = 0.0f;
            int   cnt = 0;
#pragma unroll
            for (int l = 0; l < MAX_PATH; ++l) {
                int idx = path_idx[(size_t)p * MAX_PATH + l];
                if (idx >= 0) { sum += D[(size_t)l * n_edges + idx]; ++cnt; }
            }
            float val = (cnt > 0) ? (sum / (float)cnt) : 0.0f;
            out[(size_t)src_idx[p] * N_NODES + dst_idx[p]] = val;
        }
    }
}

extern "C" void kernel_launch(void* const* d_in, const int* in_sizes, int n_in,
                              void* d_out, int out_size, void* d_ws, size_t ws_size,
                              hipStream_t stream)
{
    // Input order: x, edge_attr, edge_vector, src_idx, dst_idx, path_idx
    const float* edge_attr   = (const float*)d_in[1];
    const float* edge_vector = (const float*)d_in[2];
    const int*   src_idx     = (const int*)d_in[3];
    const int*   dst_idx     = (const int*)d_in[4];
    const int*   path_idx    = (const int*)d_in[5];
    float*       out         = (float*)d_out;
    float*       D           = (float*)d_ws;   // 5*E*4B = 2 MB

    const int n_edges = in_sizes[1] / EDGE_DIM;  // 100,000
    const int n_pairs = in_sizes[3];             // 1,000,000

    // K1: fill(2048 blocks) + precompute D (~391 blocks), disjoint outputs.
    const int pre_blocks = (n_edges + BLOCK - 1) / BLOCK;
    fill_and_precompute_kernel<<<FILL_BLOCKS + pre_blocks, BLOCK, 0, stream>>>(
        edge_attr, edge_vector, D, out, n_edges);

    // K2: fused gather + scatter (kernel boundary orders fill & D before use).
    const int t2 = (n_pairs + 1) / 2;
    gather_scatter_kernel<<<(t2 + BLOCK - 1) / BLOCK, BLOCK, 0, stream>>>(
        D, src_idx, dst_idx, path_idx, out, n_pairs, n_edges);
}